// Round 1
// baseline (443.080 us; speedup 1.0000x reference)
//
#include <hip/hip_runtime.h>
#include <math.h>

#define Bn   8
#define DIM  128
#define Hs   64
#define Ws   64
#define PADn 3
#define GC   16
#define Gn   8
#define CMID 32    // DIM/RED
#define NW   392   // K*K*G

// ---------------- K1: t = relu(bn(conv1(x))) ----------------
__global__ __launch_bounds__(256) void k1_t(const float* __restrict__ x,
        const float* __restrict__ w1, const float* __restrict__ b1v,
        const float* __restrict__ bng, const float* __restrict__ bnb,
        const float* __restrict__ bnm, const float* __restrict__ bnv,
        float* __restrict__ tout) {
    __shared__ float xs[DIM][Ws];   // 32KB
    int b = blockIdx.x >> 6, h = blockIdx.x & 63;
    int tid = threadIdx.x;
    for (int i = tid; i < DIM * Ws; i += 256) {
        int c = i >> 6, w = i & 63;
        xs[c][w] = x[(((size_t)b * DIM + c) * Hs + h) * Ws + w];
    }
    __syncthreads();
    int w = tid & 63, oq = tid >> 6;   // oq: 0..3, 8 outputs each
    float acc[8];
#pragma unroll
    for (int k = 0; k < 8; ++k) acc[k] = 0.f;
    for (int c = 0; c < DIM; ++c) {
        float xv = xs[c][w];
#pragma unroll
        for (int k = 0; k < 8; ++k) {
            int o = oq * 8 + k;
            acc[k] = fmaf(w1[o * DIM + c], xv, acc[k]);
        }
    }
#pragma unroll
    for (int k = 0; k < 8; ++k) {
        int o = oq * 8 + k;
        float sc = bng[o] * rsqrtf(bnv[o] + 1e-5f);
        float v = (acc[k] + b1v[o]) * sc + (bnb[o] - bnm[o] * sc);
        tout[(((size_t)b * CMID + o) * Hs + h) * Ws + w] = fmaxf(v, 0.f);
    }
}

// ------- K2: wgt = conv2(t); involution; LayerNorm; y_ln [pix,128] -------
__global__ __launch_bounds__(256) void k2_inv_ln(const float* __restrict__ x,
        const float* __restrict__ tin,
        const float* __restrict__ w2, const float* __restrict__ b2v,
        const float* __restrict__ lng, const float* __restrict__ lnb,
        float* __restrict__ yln) {
    __shared__ float ys[DIM][Ws + 1];     // 33.3KB (stride 65: conflict-free)
    __shared__ float wgt[49][Ws];         // 12.5KB
    __shared__ float xp[GC][7][70];       // 31.4KB
    __shared__ float mu_s[Ws], rs_s[Ws];
    int b = blockIdx.x >> 6, h = blockIdx.x & 63;
    int tid = threadIdx.x;
    int w = tid & 63, q = tid >> 6;       // q: 0..3

    // hoist this w's t-column (32 values) to registers
    float tv[CMID];
#pragma unroll
    for (int c = 0; c < CMID; ++c)
        tv[c] = tin[(((size_t)b * CMID + c) * Hs + h) * Ws + w];

    for (int g = 0; g < Gn; ++g) {
        // involution weights: wgt[p][w], p strided by q
        for (int p = q; p < 49; p += 4) {
            int o = g * 49 + p;
            float acc = b2v[o];
#pragma unroll
            for (int c = 0; c < CMID; ++c)
                acc = fmaf(w2[o * CMID + c], tv[c], acc);
            wgt[p][w] = acc;
        }
        // stage padded x patch for this group: 16ch x 7rows x 70cols
        for (int i = tid; i < GC * 7 * 70; i += 256) {
            int cc = i / 490;
            int rem = i % 490;
            int r = rem / 70, col = rem % 70;
            int hh = h + r - PADn, wc = col - PADn;
            float v = 0.f;
            if ((unsigned)hh < (unsigned)Hs && (unsigned)wc < (unsigned)Ws)
                v = x[(((size_t)b * DIM + g * GC + cc) * Hs + hh) * Ws + wc];
            xp[cc][r][col] = v;
        }
        __syncthreads();
        // involution: 4 channels per thread, 49 taps each (wgt hoisted)
        float wv[49];
#pragma unroll
        for (int p = 0; p < 49; ++p) wv[p] = wgt[p][w];
#pragma unroll
        for (int k = 0; k < 4; ++k) {
            int cc = q + k * 4;
            float acc = 0.f;
#pragma unroll
            for (int r = 0; r < 7; ++r)
#pragma unroll
                for (int j = 0; j < 7; ++j)
                    acc = fmaf(wv[r * 7 + j], xp[cc][r][w + j], acc);
            ys[g * GC + cc][w] = acc;
        }
        __syncthreads();
    }

    // LayerNorm over channels, one pixel per lane (wave 0..0 only, 64 lanes x2)
    if (tid < Ws) {
        float s = 0.f, ss = 0.f;
#pragma unroll 4
        for (int c = 0; c < DIM; ++c) {
            float v = ys[c][tid];
            s += v; ss = fmaf(v, v, ss);
        }
        float mu = s * (1.f / DIM);
        float var = ss * (1.f / DIM) - mu * mu;
        mu_s[tid] = mu;
        rs_s[tid] = rsqrtf(var + 1e-6f);
    }
    __syncthreads();
    size_t pbase = ((size_t)b * Hs + h) * Ws;
    for (int i = tid; i < Ws * DIM; i += 256) {
        int ww = i >> 7, c = i & 127;
        float v = (ys[c][ww] - mu_s[ww]) * rs_s[ww] * lng[c] + lnb[c];
        yln[(pbase + ww) * DIM + c] = v;
    }
}

// ---------------- K3: MLP (pw1+gelu+pw2) + residual ----------------
__global__ __launch_bounds__(256) void k3_mlp(const float* __restrict__ yln,
        const float* __restrict__ x,
        const float* __restrict__ w1, const float* __restrict__ b1v,
        const float* __restrict__ w2, const float* __restrict__ b2v,
        float* __restrict__ out) {
    __shared__ float yt[Ws][DIM + 4];     // stride 132 (==4 mod 32): b128-friendly
    __shared__ float zt[Ws][DIM + 4];     // one half (128 f) of z
    int b = blockIdx.x >> 6, h = blockIdx.x & 63;
    int tid = threadIdx.x;
    int w = tid & 63, q = tid >> 6;
    size_t pbase = ((size_t)b * Hs + h) * Ws;
    for (int i = tid; i < Ws * DIM; i += 256) {
        int ww = i >> 7, c = i & 127;
        yt[ww][c] = yln[(pbase + ww) * DIM + c];
    }
    __syncthreads();
    float oacc[32];
#pragma unroll
    for (int k = 0; k < 32; ++k) oacc[k] = 0.f;

    for (int half = 0; half < 2; ++half) {
        // z[f], f = half*128 + q*32 + k  (32 dots of 128 per thread)
        float zacc[32];
#pragma unroll
        for (int k = 0; k < 32; ++k) zacc[k] = b1v[half * 128 + q * 32 + k];
        for (int c = 0; c < DIM; c += 4) {
            float4 yv = *(const float4*)&yt[w][c];
#pragma unroll
            for (int k = 0; k < 32; ++k) {
                int f = half * 128 + q * 32 + k;
                float4 wv = *(const float4*)&w1[f * DIM + c];
                zacc[k] = fmaf(wv.x, yv.x, zacc[k]);
                zacc[k] = fmaf(wv.y, yv.y, zacc[k]);
                zacc[k] = fmaf(wv.z, yv.z, zacc[k]);
                zacc[k] = fmaf(wv.w, yv.w, zacc[k]);
            }
        }
#pragma unroll
        for (int k = 0; k < 32; ++k) {
            float v = zacc[k];
            v = v * 0.5f * (1.f + erff(v * 0.70710678118f));
            zt[w][q * 32 + k] = v;
        }
        __syncthreads();
        // out[c] partial: c = q*32 + k, over this half's 128 f
        for (int f = 0; f < DIM; f += 4) {
            float4 zv = *(const float4*)&zt[w][f];
#pragma unroll
            for (int k = 0; k < 32; ++k) {
                int c = q * 32 + k;
                float4 wv = *(const float4*)&w2[c * 256 + half * 128 + f];
                oacc[k] = fmaf(wv.x, zv.x, oacc[k]);
                oacc[k] = fmaf(wv.y, zv.y, oacc[k]);
                oacc[k] = fmaf(wv.z, zv.z, oacc[k]);
                oacc[k] = fmaf(wv.w, zv.w, oacc[k]);
            }
        }
        __syncthreads();
    }
#pragma unroll
    for (int k = 0; k < 32; ++k) {
        int c = q * 32 + k;
        size_t gi = (((size_t)b * DIM + c) * Hs + h) * Ws + w;
        out[gi] = oacc[k] + b2v[c] + x[gi];
    }
}

extern "C" void kernel_launch(void* const* d_in, const int* in_sizes, int n_in,
                              void* d_out, int out_size, void* d_ws, size_t ws_size,
                              hipStream_t stream) {
    const float* x       = (const float*)d_in[0];
    const float* conv1_w = (const float*)d_in[1];
    const float* conv1_b = (const float*)d_in[2];
    const float* bn_g    = (const float*)d_in[3];
    const float* bn_b    = (const float*)d_in[4];
    const float* bn_mean = (const float*)d_in[5];
    const float* bn_var  = (const float*)d_in[6];
    const float* conv2_w = (const float*)d_in[7];
    const float* conv2_b = (const float*)d_in[8];
    const float* ln_g    = (const float*)d_in[9];
    const float* ln_b    = (const float*)d_in[10];
    const float* pw1_w   = (const float*)d_in[11];
    const float* pw1_b   = (const float*)d_in[12];
    const float* pw2_w   = (const float*)d_in[13];
    const float* pw2_b   = (const float*)d_in[14];
    float* out = (float*)d_out;

    float* t_buf = (float*)d_ws;                                   // 4 MB
    float* y_ln  = (float*)((char*)d_ws + (size_t)Bn * CMID * Hs * Ws * 4); // 16.8 MB

    dim3 grid(Bn * Hs), block(256);
    hipLaunchKernelGGL(k1_t, grid, block, 0, stream,
                       x, conv1_w, conv1_b, bn_g, bn_b, bn_mean, bn_var, t_buf);
    hipLaunchKernelGGL(k2_inv_ln, grid, block, 0, stream,
                       x, t_buf, conv2_w, conv2_b, ln_g, ln_b, y_ln);
    hipLaunchKernelGGL(k3_mlp, grid, block, 0, stream,
                       y_ln, x, pw1_w, pw1_b, pw2_w, pw2_b, out);
}

// Round 2
// 218.055 us; speedup vs baseline: 2.0320x; 2.0320x over previous
//
#include <hip/hip_runtime.h>
#include <hip/hip_bf16.h>
#include <math.h>

#define Bn   8
#define DIM  128
#define Hs   64
#define Ws   64
#define PADn 3
#define GC   16
#define Gn   8
#define CMID 32    // DIM/RED
#define NW   392   // K*K*G

typedef __bf16 bf16x8 __attribute__((ext_vector_type(8)));
typedef float  f32x4  __attribute__((ext_vector_type(4)));

__device__ __forceinline__ f32x4 mfma16(bf16x8 a, bf16x8 b, f32x4 c) {
    return __builtin_amdgcn_mfma_f32_16x16x32_bf16(a, b, c, 0, 0, 0);
}

// ---------------- K0: convert MLP weights to bf16 ----------------
__global__ __launch_bounds__(256) void k0_cvt(const float* __restrict__ w1,
        const float* __restrict__ w2,
        __hip_bfloat16* __restrict__ w1b, __hip_bfloat16* __restrict__ w2b) {
    int i = blockIdx.x * 256 + threadIdx.x;   // grid covers 32768
    w1b[i] = __float2bfloat16(w1[i]);
    w2b[i] = __float2bfloat16(w2[i]);
}

// ---------------- K1: t = relu(bn(conv1(x))) ----------------
__global__ __launch_bounds__(256) void k1_t(const float* __restrict__ x,
        const float* __restrict__ w1, const float* __restrict__ b1v,
        const float* __restrict__ bng, const float* __restrict__ bnb,
        const float* __restrict__ bnm, const float* __restrict__ bnv,
        float* __restrict__ tout) {
    __shared__ float xs[DIM][Ws];   // 32KB
    int b = blockIdx.x >> 6, h = blockIdx.x & 63;
    int tid = threadIdx.x;
    for (int i = tid; i < DIM * Ws; i += 256) {
        int c = i >> 6, w = i & 63;
        xs[c][w] = x[(((size_t)b * DIM + c) * Hs + h) * Ws + w];
    }
    __syncthreads();
    int w = tid & 63, oq = tid >> 6;   // oq: 0..3, 8 outputs each
    float acc[8];
#pragma unroll
    for (int k = 0; k < 8; ++k) acc[k] = 0.f;
    for (int c = 0; c < DIM; ++c) {
        float xv = xs[c][w];
#pragma unroll
        for (int k = 0; k < 8; ++k) {
            int o = oq * 8 + k;
            acc[k] = fmaf(w1[o * DIM + c], xv, acc[k]);
        }
    }
#pragma unroll
    for (int k = 0; k < 8; ++k) {
        int o = oq * 8 + k;
        float sc = bng[o] * rsqrtf(bnv[o] + 1e-5f);
        float v = (acc[k] + b1v[o]) * sc + (bnb[o] - bnm[o] * sc);
        tout[(((size_t)b * CMID + o) * Hs + h) * Ws + w] = fmaxf(v, 0.f);
    }
}

// ------- K2: wgt = conv2(t); involution; LayerNorm; y_ln bf16 [pix,128] -------
__global__ __launch_bounds__(256) void k2_inv_ln(const float* __restrict__ x,
        const float* __restrict__ tin,
        const float* __restrict__ w2, const float* __restrict__ b2v,
        const float* __restrict__ lng, const float* __restrict__ lnb,
        __hip_bfloat16* __restrict__ yln) {
    __shared__ float ys[DIM][Ws + 1];     // stride 65: conflict-free
    __shared__ float wgt[49][Ws];
    __shared__ float xp[GC][7][70];
    __shared__ float mu_s[Ws], rs_s[Ws];
    int b = blockIdx.x >> 6, h = blockIdx.x & 63;
    int tid = threadIdx.x;
    int w = tid & 63, q = tid >> 6;       // q: 0..3

    float tv[CMID];
#pragma unroll
    for (int c = 0; c < CMID; ++c)
        tv[c] = tin[(((size_t)b * CMID + c) * Hs + h) * Ws + w];

    for (int g = 0; g < Gn; ++g) {
        for (int p = q; p < 49; p += 4) {
            int o = g * 49 + p;
            float acc = b2v[o];
#pragma unroll
            for (int c = 0; c < CMID; ++c)
                acc = fmaf(w2[o * CMID + c], tv[c], acc);
            wgt[p][w] = acc;
        }
        for (int i = tid; i < GC * 7 * 70; i += 256) {
            int cc = i / 490;
            int rem = i % 490;
            int r = rem / 70, col = rem % 70;
            int hh = h + r - PADn, wc = col - PADn;
            float v = 0.f;
            if ((unsigned)hh < (unsigned)Hs && (unsigned)wc < (unsigned)Ws)
                v = x[(((size_t)b * DIM + g * GC + cc) * Hs + hh) * Ws + wc];
            xp[cc][r][col] = v;
        }
        __syncthreads();
        float wv[49];
#pragma unroll
        for (int p = 0; p < 49; ++p) wv[p] = wgt[p][w];
#pragma unroll
        for (int k = 0; k < 4; ++k) {
            int cc = q + k * 4;
            float acc = 0.f;
#pragma unroll
            for (int r = 0; r < 7; ++r)
#pragma unroll
                for (int j = 0; j < 7; ++j)
                    acc = fmaf(wv[r * 7 + j], xp[cc][r][w + j], acc);
            ys[g * GC + cc][w] = acc;
        }
        __syncthreads();
    }

    if (tid < Ws) {
        float s = 0.f, ss = 0.f;
#pragma unroll 4
        for (int c = 0; c < DIM; ++c) {
            float v = ys[c][tid];
            s += v; ss = fmaf(v, v, ss);
        }
        float mu = s * (1.f / DIM);
        float var = ss * (1.f / DIM) - mu * mu;
        mu_s[tid] = mu;
        rs_s[tid] = rsqrtf(var + 1e-6f);
    }
    __syncthreads();
    size_t pbase = ((size_t)b * Hs + h) * Ws;
    for (int i = tid; i < Ws * DIM; i += 256) {
        int ww = i >> 7, c = i & 127;
        float v = (ys[c][ww] - mu_s[ww]) * rs_s[ww] * lng[c] + lnb[c];
        yln[(pbase + ww) * DIM + c] = __float2bfloat16(v);
    }
}

// ---------------- K3: MLP via bf16 MFMA + residual ----------------
__global__ __launch_bounds__(256) void k3_mlp_mfma(
        const __hip_bfloat16* __restrict__ yln,   // [P][128] bf16
        const float* __restrict__ x,
        const __hip_bfloat16* __restrict__ w1b,   // [256][128] bf16
        const float* __restrict__ b1v,
        const __hip_bfloat16* __restrict__ w2b,   // [128][256] bf16
        const float* __restrict__ b2v,
        float* __restrict__ out) {
    __shared__ __align__(16) union {
        __hip_bfloat16 y[64][136];   // 17.4KB, phase 1 (row stride 272B: 2-way banks)
        float          o[64][133];   // 34.0KB, phase 3 (stride 133w: 2-way banks)
    } u;
    __shared__ __align__(16) __hip_bfloat16 zsh[4][16][264]; // 33.8KB (stride 528B)

    int b = blockIdx.x >> 6, h = blockIdx.x & 63;
    int tid = threadIdx.x;
    int lane = tid & 63, wid = tid >> 6;
    int l15 = lane & 15, l4 = lane >> 4;
    size_t pbase = ((size_t)b * Hs + h) * Ws;

    // stage Y tile: 64 rows x 128 bf16, 16B chunks, coalesced
    for (int i = tid; i < 64 * 16; i += 256) {
        int row = i >> 4, ch = i & 15;
        *(ulonglong2*)&u.y[row][ch * 8] =
            *(const ulonglong2*)&yln[(pbase + row) * DIM + ch * 8];
    }
    __syncthreads();

    int m0 = wid * 16;

    // ---- GEMM1: Z[16 pix][256] = Y[16][128] @ W1^T, K-steps of 32 ----
    f32x4 acc[16];
#pragma unroll
    for (int n = 0; n < 16; ++n) acc[n] = (f32x4){0.f, 0.f, 0.f, 0.f};
#pragma unroll
    for (int ks = 0; ks < 4; ++ks) {
        bf16x8 a = *(const bf16x8*)&u.y[m0 + l15][ks * 32 + l4 * 8];
#pragma unroll
        for (int n = 0; n < 16; ++n) {
            bf16x8 bf = *(const bf16x8*)&w1b[(n * 16 + l15) * DIM + ks * 32 + l4 * 8];
            acc[n] = mfma16(a, bf, acc[n]);
        }
    }
    __syncthreads();   // all waves done reading u.y (u reused as u.o later)

    // ---- bias + exact gelu + bf16 -> zsh (wave-private slice) ----
#pragma unroll
    for (int n = 0; n < 16; ++n) {
        float bv = b1v[n * 16 + l15];
#pragma unroll
        for (int r = 0; r < 4; ++r) {
            float v = acc[n][r] + bv;
            v = v * 0.5f * (1.f + erff(v * 0.70710678118f));
            zsh[wid][l4 * 4 + r][n * 16 + l15] = __float2bfloat16(v);
        }
    }

    // ---- GEMM2: out[16 pix][128] = G[16][256] @ W2^T ----
    f32x4 acc2[8];
#pragma unroll
    for (int n = 0; n < 8; ++n) acc2[n] = (f32x4){0.f, 0.f, 0.f, 0.f};
#pragma unroll
    for (int ks = 0; ks < 8; ++ks) {
        bf16x8 a = *(const bf16x8*)&zsh[wid][l15][ks * 32 + l4 * 8];
#pragma unroll
        for (int n = 0; n < 8; ++n) {
            bf16x8 bf = *(const bf16x8*)&w2b[(n * 16 + l15) * 256 + ks * 32 + l4 * 8];
            acc2[n] = mfma16(a, bf, acc2[n]);
        }
    }

    // ---- bias -> LDS transpose ----
#pragma unroll
    for (int n = 0; n < 8; ++n) {
        float bv = b2v[n * 16 + l15];
#pragma unroll
        for (int r = 0; r < 4; ++r)
            u.o[m0 + l4 * 4 + r][n * 16 + l15] = acc2[n][r] + bv;
    }
    __syncthreads();

    // ---- coalesced channel-major store + residual ----
    for (int i = tid; i < Ws * DIM; i += 256) {
        int c = i >> 6, w = i & 63;
        size_t gi = (((size_t)b * DIM + c) * Hs + h) * Ws + w;
        out[gi] = u.o[w][c] + x[gi];
    }
}

extern "C" void kernel_launch(void* const* d_in, const int* in_sizes, int n_in,
                              void* d_out, int out_size, void* d_ws, size_t ws_size,
                              hipStream_t stream) {
    const float* x       = (const float*)d_in[0];
    const float* conv1_w = (const float*)d_in[1];
    const float* conv1_b = (const float*)d_in[2];
    const float* bn_g    = (const float*)d_in[3];
    const float* bn_b    = (const float*)d_in[4];
    const float* bn_mean = (const float*)d_in[5];
    const float* bn_var  = (const float*)d_in[6];
    const float* conv2_w = (const float*)d_in[7];
    const float* conv2_b = (const float*)d_in[8];
    const float* ln_g    = (const float*)d_in[9];
    const float* ln_b    = (const float*)d_in[10];
    const float* pw1_w   = (const float*)d_in[11];
    const float* pw1_b   = (const float*)d_in[12];
    const float* pw2_w   = (const float*)d_in[13];
    const float* pw2_b   = (const float*)d_in[14];
    float* out = (float*)d_out;

    char* ws = (char*)d_ws;
    float* t_buf          = (float*)ws;                          // 4 MB
    __hip_bfloat16* y_ln  = (__hip_bfloat16*)(ws + 4194304);     // 8.39 MB
    __hip_bfloat16* w1b   = (__hip_bfloat16*)(ws + 4194304 + 8388608);
    __hip_bfloat16* w2b   = (__hip_bfloat16*)(ws + 4194304 + 8388608 + 65536);

    dim3 block(256);
    hipLaunchKernelGGL(k0_cvt, dim3(128), block, 0, stream, pw1_w, pw2_w, w1b, w2b);
    hipLaunchKernelGGL(k1_t, dim3(Bn * Hs), block, 0, stream,
                       x, conv1_w, conv1_b, bn_g, bn_b, bn_mean, bn_var, t_buf);
    hipLaunchKernelGGL(k2_inv_ln, dim3(Bn * Hs), block, 0, stream,
                       x, t_buf, conv2_w, conv2_b, ln_g, ln_b, y_ln);
    hipLaunchKernelGGL(k3_mlp_mfma, dim3(Bn * Hs), block, 0, stream,
                       y_ln, x, w1b, pw1_b, w2b, pw2_b, out);
}

// Round 3
// 198.312 us; speedup vs baseline: 2.2343x; 1.0996x over previous
//
#include <hip/hip_runtime.h>
#include <hip/hip_bf16.h>
#include <math.h>

#define Bn   8
#define DIM  128
#define Hs   64
#define Ws   64
#define PADn 3
#define GC   16
#define Gn   8
#define CMID 32    // DIM/RED
#define NW   392   // K*K*G
#define NWP  416   // w2b padded rows

typedef __bf16 bf16x8 __attribute__((ext_vector_type(8)));
typedef float  f32x4  __attribute__((ext_vector_type(4)));

__device__ __forceinline__ f32x4 mfma16(bf16x8 a, bf16x8 b, f32x4 c) {
    return __builtin_amdgcn_mfma_f32_16x16x32_bf16(a, b, c, 0, 0, 0);
}

__device__ __forceinline__ __bf16 tobf(float v) {
    __hip_bfloat16 h = __float2bfloat16(v);
    return *reinterpret_cast<__bf16*>(&h);
}

// ---------------- K0: convert weights to bf16 ----------------
__global__ __launch_bounds__(256) void k0_cvt(const float* __restrict__ w1,
        const float* __restrict__ w2,
        const float* __restrict__ pw1, const float* __restrict__ pw2,
        __hip_bfloat16* __restrict__ w1b, __hip_bfloat16* __restrict__ w2b,
        __hip_bfloat16* __restrict__ mw1b, __hip_bfloat16* __restrict__ mw2b) {
    int i = blockIdx.x * 256 + threadIdx.x;   // 32768 threads
    if (i < CMID * DIM) w1b[i] = __float2bfloat16(w1[i]);
    if (i < NWP * CMID)
        w2b[i] = (i < NW * CMID) ? __float2bfloat16(w2[i]) : __float2bfloat16(0.f);
    mw1b[i] = __float2bfloat16(pw1[i]);
    mw2b[i] = __float2bfloat16(pw2[i]);
}

// ---------------- K1: t = relu(bn(conv1(x))) via MFMA, t bf16 [pix][32] ----------------
__global__ __launch_bounds__(256) void k1_conv1(const float* __restrict__ x,
        const __hip_bfloat16* __restrict__ w1b, const float* __restrict__ b1v,
        const float* __restrict__ bng, const float* __restrict__ bnb,
        const float* __restrict__ bnm, const float* __restrict__ bnv,
        __hip_bfloat16* __restrict__ t_bf) {
    int b = blockIdx.x >> 6, h = blockIdx.x & 63;
    int tid = threadIdx.x, lane = tid & 63, wid = tid >> 6;
    int l15 = lane & 15, l4 = lane >> 4;
    int m0 = wid * 16;

    // A-frags: pixel row = m0+l15, k = ks*32 + l4*8 + i (channel)
    bf16x8 afr[4];
#pragma unroll
    for (int ks = 0; ks < 4; ++ks) {
#pragma unroll
        for (int i = 0; i < 8; ++i) {
            int c = ks * 32 + l4 * 8 + i;
            float xv = x[(((size_t)b * DIM + c) * Hs + h) * Ws + m0 + l15];
            afr[ks][i] = tobf(xv);
        }
    }
    f32x4 acc[2];
#pragma unroll
    for (int nt = 0; nt < 2; ++nt) acc[nt] = (f32x4){0.f, 0.f, 0.f, 0.f};
#pragma unroll
    for (int nt = 0; nt < 2; ++nt)
#pragma unroll
        for (int ks = 0; ks < 4; ++ks) {
            bf16x8 bf = *(const bf16x8*)&w1b[(nt * 16 + l15) * DIM + ks * 32 + l4 * 8];
            acc[nt] = mfma16(afr[ks], bf, acc[nt]);
        }
    size_t pbase = (size_t)b * 4096 + (size_t)h * 64;
#pragma unroll
    for (int nt = 0; nt < 2; ++nt) {
        int o = nt * 16 + l15;
        float sc = bng[o] * rsqrtf(bnv[o] + 1e-5f);
        float sh = bnb[o] - bnm[o] * sc;
        float bv = b1v[o];
#pragma unroll
        for (int r = 0; r < 4; ++r) {
            float v = (acc[nt][r] + bv) * sc + sh;
            v = fmaxf(v, 0.f);
            size_t pix = pbase + m0 + l4 * 4 + r;
            t_bf[pix * CMID + o] = __float2bfloat16(v);
        }
    }
}

// ------- K2: conv2 via MFMA; involution; LayerNorm; y_ln bf16 [pix][128] -------
__global__ __launch_bounds__(256) void k2_inv_ln(const float* __restrict__ x,
        const __hip_bfloat16* __restrict__ t_bf,
        const __hip_bfloat16* __restrict__ w2b, const float* __restrict__ b2v,
        const float* __restrict__ lng, const float* __restrict__ lnb,
        __hip_bfloat16* __restrict__ yln) {
    __shared__ float ys[DIM][Ws + 1];            // 33.3 KB
    __shared__ __hip_bfloat16 xp[GC][7][72];     // 16.1 KB
    __shared__ float wgt[49][66];                // 12.9 KB
    __shared__ float ps[4][64], pss[4][64];      // 2 KB
    __shared__ float mu_s[64], rs_s[64];
    int b = blockIdx.x >> 6, h = blockIdx.x & 63;
    int tid = threadIdx.x, lane = tid & 63, wid = tid >> 6;
    int l15 = lane & 15, l4 = lane >> 4;
    int m0 = wid * 16;
    int w = tid & 63, q = tid >> 6;              // involution roles (q uniform per wave)
    size_t pbase = (size_t)b * 4096 + (size_t)h * 64;

    // hoisted conv2 A-frag (K=32 total: single fragment), coalesced 16B load
    bf16x8 a_t = *(const bf16x8*)&t_bf[(pbase + m0 + l15) * CMID + l4 * 8];

    for (int g = 0; g < Gn; ++g) {
        // conv2 MFMA: N = 49 (4 tiles of 16, padded weights)
        f32x4 acc[4];
#pragma unroll
        for (int nt = 0; nt < 4; ++nt) acc[nt] = (f32x4){0.f, 0.f, 0.f, 0.f};
#pragma unroll
        for (int nt = 0; nt < 4; ++nt) {
            bf16x8 bf = *(const bf16x8*)&w2b[(size_t)(g * 49 + nt * 16 + l15) * CMID + l4 * 8];
            acc[nt] = mfma16(a_t, bf, acc[nt]);
        }
#pragma unroll
        for (int nt = 0; nt < 4; ++nt) {
            int p = nt * 16 + l15;
            if (p < 49) {
                float bias = b2v[g * 49 + p];
#pragma unroll
                for (int r = 0; r < 4; ++r)
                    wgt[p][m0 + l4 * 4 + r] = acc[nt][r] + bias;
            }
        }
        // stage padded x patch (bf16): 16ch x 7rows x 70cols
        for (int i = tid; i < GC * 7 * 70; i += 256) {
            int cc = i / 490;
            int rem = i - cc * 490;
            int r = rem / 70, col = rem - r * 70;
            int hh = h + r - PADn, wc = col - PADn;
            float v = 0.f;
            if ((unsigned)hh < (unsigned)Hs && (unsigned)wc < (unsigned)Ws)
                v = x[(((size_t)b * DIM + g * GC + cc) * Hs + hh) * Ws + wc];
            xp[cc][r][col] = __float2bfloat16(v);
        }
        __syncthreads();
        // involution: 4 channels per thread, 49 taps each
        float wv[49];
#pragma unroll
        for (int p = 0; p < 49; ++p) wv[p] = wgt[p][w];
#pragma unroll
        for (int k = 0; k < 4; ++k) {
            int cc = q + k * 4;
            float a2 = 0.f;
#pragma unroll
            for (int r = 0; r < 7; ++r)
#pragma unroll
                for (int j = 0; j < 7; ++j)
                    a2 = fmaf(wv[r * 7 + j], __bfloat162float(xp[cc][r][w + j]), a2);
            ys[g * GC + cc][w] = a2;
        }
        __syncthreads();
    }

    // LayerNorm: 4 partial sums per pixel
    {
        int part = tid >> 6;  // uniform per wave
        float s = 0.f, ss = 0.f;
#pragma unroll
        for (int c = 0; c < 32; ++c) {
            float v = ys[part * 32 + c][w];
            s += v; ss = fmaf(v, v, ss);
        }
        ps[part][w] = s; pss[part][w] = ss;
    }
    __syncthreads();
    if (tid < 64) {
        float s = ps[0][tid] + ps[1][tid] + ps[2][tid] + ps[3][tid];
        float ss = pss[0][tid] + pss[1][tid] + pss[2][tid] + pss[3][tid];
        float mu = s * (1.f / DIM);
        float var = ss * (1.f / DIM) - mu * mu;
        mu_s[tid] = mu;
        rs_s[tid] = rsqrtf(var + 1e-6f);
    }
    __syncthreads();
    for (int i = tid; i < Ws * DIM; i += 256) {
        int ww = i >> 7, c = i & 127;
        float v = (ys[c][ww] - mu_s[ww]) * rs_s[ww] * lng[c] + lnb[c];
        yln[(pbase + ww) * DIM + c] = __float2bfloat16(v);
    }
}

// ---------------- K3: MLP via bf16 MFMA + residual ----------------
__global__ __launch_bounds__(256) void k3_mlp_mfma(
        const __hip_bfloat16* __restrict__ yln,   // [P][128] bf16
        const float* __restrict__ x,
        const __hip_bfloat16* __restrict__ w1b,   // [256][128] bf16
        const float* __restrict__ b1v,
        const __hip_bfloat16* __restrict__ w2b,   // [128][256] bf16
        const float* __restrict__ b2v,
        float* __restrict__ out) {
    __shared__ __align__(16) union {
        __hip_bfloat16 y[64][136];
        float          o[64][133];
    } u;
    __shared__ __align__(16) __hip_bfloat16 zsh[4][16][264];

    int b = blockIdx.x >> 6, h = blockIdx.x & 63;
    int tid = threadIdx.x;
    int lane = tid & 63, wid = tid >> 6;
    int l15 = lane & 15, l4 = lane >> 4;
    size_t pbase = ((size_t)b * Hs + h) * Ws;

    for (int i = tid; i < 64 * 16; i += 256) {
        int row = i >> 4, ch = i & 15;
        *(ulonglong2*)&u.y[row][ch * 8] =
            *(const ulonglong2*)&yln[(pbase + row) * DIM + ch * 8];
    }
    __syncthreads();

    int m0 = wid * 16;

    f32x4 acc[16];
#pragma unroll
    for (int n = 0; n < 16; ++n) acc[n] = (f32x4){0.f, 0.f, 0.f, 0.f};
#pragma unroll
    for (int ks = 0; ks < 4; ++ks) {
        bf16x8 a = *(const bf16x8*)&u.y[m0 + l15][ks * 32 + l4 * 8];
#pragma unroll
        for (int n = 0; n < 16; ++n) {
            bf16x8 bf = *(const bf16x8*)&w1b[(n * 16 + l15) * DIM + ks * 32 + l4 * 8];
            acc[n] = mfma16(a, bf, acc[n]);
        }
    }
    __syncthreads();

#pragma unroll
    for (int n = 0; n < 16; ++n) {
        float bv = b1v[n * 16 + l15];
#pragma unroll
        for (int r = 0; r < 4; ++r) {
            float v = acc[n][r] + bv;
            v = v * 0.5f * (1.f + erff(v * 0.70710678118f));
            zsh[wid][l4 * 4 + r][n * 16 + l15] = __float2bfloat16(v);
        }
    }

    f32x4 acc2[8];
#pragma unroll
    for (int n = 0; n < 8; ++n) acc2[n] = (f32x4){0.f, 0.f, 0.f, 0.f};
#pragma unroll
    for (int ks = 0; ks < 8; ++ks) {
        bf16x8 a = *(const bf16x8*)&zsh[wid][l15][ks * 32 + l4 * 8];
#pragma unroll
        for (int n = 0; n < 8; ++n) {
            bf16x8 bf = *(const bf16x8*)&w2b[(n * 16 + l15) * 256 + ks * 32 + l4 * 8];
            acc2[n] = mfma16(a, bf, acc2[n]);
        }
    }

#pragma unroll
    for (int n = 0; n < 8; ++n) {
        float bv = b2v[n * 16 + l15];
#pragma unroll
        for (int r = 0; r < 4; ++r)
            u.o[m0 + l4 * 4 + r][n * 16 + l15] = acc2[n][r] + bv;
    }
    __syncthreads();

    for (int i = tid; i < Ws * DIM; i += 256) {
        int c = i >> 6, w = i & 63;
        size_t gi = (((size_t)b * DIM + c) * Hs + h) * Ws + w;
        out[gi] = u.o[w][c] + x[gi];
    }
}

extern "C" void kernel_launch(void* const* d_in, const int* in_sizes, int n_in,
                              void* d_out, int out_size, void* d_ws, size_t ws_size,
                              hipStream_t stream) {
    const float* x       = (const float*)d_in[0];
    const float* conv1_w = (const float*)d_in[1];
    const float* conv1_b = (const float*)d_in[2];
    const float* bn_g    = (const float*)d_in[3];
    const float* bn_b    = (const float*)d_in[4];
    const float* bn_mean = (const float*)d_in[5];
    const float* bn_var  = (const float*)d_in[6];
    const float* conv2_w = (const float*)d_in[7];
    const float* conv2_b = (const float*)d_in[8];
    const float* ln_g    = (const float*)d_in[9];
    const float* ln_b    = (const float*)d_in[10];
    const float* pw1_w   = (const float*)d_in[11];
    const float* pw1_b   = (const float*)d_in[12];
    const float* pw2_w   = (const float*)d_in[13];
    const float* pw2_b   = (const float*)d_in[14];
    float* out = (float*)d_out;

    char* ws = (char*)d_ws;
    __hip_bfloat16* t_bf = (__hip_bfloat16*)ws;                      // 2 MB
    __hip_bfloat16* y_ln = (__hip_bfloat16*)(ws + 2097152);          // 8 MB
    __hip_bfloat16* w1b  = (__hip_bfloat16*)(ws + 10485760);         // 8 KB
    __hip_bfloat16* w2b  = (__hip_bfloat16*)(ws + 10493952);         // 26 KB
    __hip_bfloat16* mw1b = (__hip_bfloat16*)(ws + 10520576);         // 64 KB
    __hip_bfloat16* mw2b = (__hip_bfloat16*)(ws + 10586112);         // 64 KB

    dim3 block(256);
    hipLaunchKernelGGL(k0_cvt, dim3(128), block, 0, stream,
                       conv1_w, conv2_w, pw1_w, pw2_w, w1b, w2b, mw1b, mw2b);
    hipLaunchKernelGGL(k1_conv1, dim3(Bn * Hs), block, 0, stream,
                       x, w1b, conv1_b, bn_g, bn_b, bn_mean, bn_var, t_bf);
    hipLaunchKernelGGL(k2_inv_ln, dim3(Bn * Hs), block, 0, stream,
                       x, t_bf, w2b, conv2_b, ln_g, ln_b, y_ln);
    hipLaunchKernelGGL(k3_mlp_mfma, dim3(Bn * Hs), block, 0, stream,
                       y_ln, x, mw1b, pw1_b, mw2b, pw2_b, out);
}

// Round 4
// 103.742 us; speedup vs baseline: 4.2710x; 1.9116x over previous
//
#include <hip/hip_runtime.h>
#include <hip/hip_bf16.h>
#include <math.h>

#define Bn   8
#define DIM  128
#define Hs   64
#define Ws   64
#define PADn 3
#define GC   16
#define Gn   8
#define CMID 32    // DIM/RED
#define NW   392   // K*K*G
#define NWP  416   // w2b padded rows

typedef __bf16 bf16x8 __attribute__((ext_vector_type(8)));
typedef float  f32x4  __attribute__((ext_vector_type(4)));
typedef _Float16 h2v  __attribute__((ext_vector_type(2)));

__device__ __forceinline__ f32x4 mfma16(bf16x8 a, bf16x8 b, f32x4 c) {
    return __builtin_amdgcn_mfma_f32_16x16x32_bf16(a, b, c, 0, 0, 0);
}

__device__ __forceinline__ __bf16 tobf(float v) {
    __hip_bfloat16 h = __float2bfloat16(v);
    return *reinterpret_cast<__bf16*>(&h);
}

// ---------------- K0: convert weights to bf16 ----------------
__global__ __launch_bounds__(256) void k0_cvt(const float* __restrict__ w1,
        const float* __restrict__ w2,
        const float* __restrict__ pw1, const float* __restrict__ pw2,
        __hip_bfloat16* __restrict__ w1b, __hip_bfloat16* __restrict__ w2b,
        __hip_bfloat16* __restrict__ mw1b, __hip_bfloat16* __restrict__ mw2b) {
    int i = blockIdx.x * 256 + threadIdx.x;   // 32768 threads
    if (i < CMID * DIM) w1b[i] = __float2bfloat16(w1[i]);
    if (i < NWP * CMID)
        w2b[i] = (i < NW * CMID) ? __float2bfloat16(w2[i]) : __float2bfloat16(0.f);
    mw1b[i] = __float2bfloat16(pw1[i]);
    mw2b[i] = __float2bfloat16(pw2[i]);
}

// ---------------- K1: t = relu(bn(conv1(x))) via MFMA, t bf16 [pix][32] ----------------
__global__ __launch_bounds__(256) void k1_conv1(const float* __restrict__ x,
        const __hip_bfloat16* __restrict__ w1b, const float* __restrict__ b1v,
        const float* __restrict__ bng, const float* __restrict__ bnb,
        const float* __restrict__ bnm, const float* __restrict__ bnv,
        __hip_bfloat16* __restrict__ t_bf) {
    int b = blockIdx.x & 7, h = blockIdx.x >> 3;   // XCD-aware: batch b -> XCD b
    int tid = threadIdx.x, lane = tid & 63, wid = tid >> 6;
    int l15 = lane & 15, l4 = lane >> 4;
    int m0 = wid * 16;

    bf16x8 afr[4];
#pragma unroll
    for (int ks = 0; ks < 4; ++ks) {
#pragma unroll
        for (int i = 0; i < 8; ++i) {
            int c = ks * 32 + l4 * 8 + i;
            float xv = x[(((size_t)b * DIM + c) * Hs + h) * Ws + m0 + l15];
            afr[ks][i] = tobf(xv);
        }
    }
    f32x4 acc[2];
#pragma unroll
    for (int nt = 0; nt < 2; ++nt) acc[nt] = (f32x4){0.f, 0.f, 0.f, 0.f};
#pragma unroll
    for (int nt = 0; nt < 2; ++nt)
#pragma unroll
        for (int ks = 0; ks < 4; ++ks) {
            bf16x8 bf = *(const bf16x8*)&w1b[(nt * 16 + l15) * DIM + ks * 32 + l4 * 8];
            acc[nt] = mfma16(afr[ks], bf, acc[nt]);
        }
    size_t pbase = (size_t)b * 4096 + (size_t)h * 64;
#pragma unroll
    for (int nt = 0; nt < 2; ++nt) {
        int o = nt * 16 + l15;
        float sc = bng[o] * rsqrtf(bnv[o] + 1e-5f);
        float sh = bnb[o] - bnm[o] * sc;
        float bv = b1v[o];
#pragma unroll
        for (int r = 0; r < 4; ++r) {
            float v = (acc[nt][r] + bv) * sc + sh;
            v = fmaxf(v, 0.f);
            size_t pix = pbase + m0 + l4 * 4 + r;
            t_bf[pix * CMID + o] = __float2bfloat16(v);
        }
    }
}

// ------- K2: conv2 MFMA; involution (pk f16); LayerNorm; y_ln bf16 [pix][128] -------
__global__ __launch_bounds__(256) void k2_inv_ln(const float* __restrict__ x,
        const __hip_bfloat16* __restrict__ t_bf,
        const __hip_bfloat16* __restrict__ w2b, const float* __restrict__ b2v,
        const float* __restrict__ lng, const float* __restrict__ lnb,
        __hip_bfloat16* __restrict__ yln) {
    __shared__ h2v  xp2[2][8][7][72];            // 32.25 KB, double-buffered
    __shared__ h2v  wgt2[49][66];                // 12.9 KB (dup f16 pairs)
    __shared__ __hip_bfloat16 ysb[DIM][66];      // 16.9 KB
    __shared__ float ps[4][64], pss[4][64];      // 2 KB
    __shared__ float mu_s[64], rs_s[64];
    int b = blockIdx.x & 7, h = blockIdx.x >> 3;   // XCD-aware
    int tid = threadIdx.x, lane = tid & 63, wid = tid >> 6;
    int l15 = lane & 15, l4 = lane >> 4;
    int m0 = wid * 16;
    int w = tid & 63, q = tid >> 6;
    size_t pbase = (size_t)b * 4096 + (size_t)h * 64;

    // hoisted conv2 A-frag (K=32: single fragment per pixel tile)
    bf16x8 a_t = *(const bf16x8*)&t_bf[(pbase + m0 + l15) * CMID + l4 * 8];

    // stage group g's x patch into xp2[buf]: pairs (cc, cc+8), f16x2
    auto stage = [&](int g, int buf) {
        for (int i = tid; i < 8 * 7 * 70; i += 256) {   // 3920 elems
            int ccp = i / 490;
            int rem = i - ccp * 490;
            int r = rem / 70, col = rem - r * 70;
            int hh = h + r - PADn, wc = col - PADn;
            float v0 = 0.f, v1 = 0.f;
            if ((unsigned)hh < (unsigned)Hs && (unsigned)wc < (unsigned)Ws) {
                size_t base = (((size_t)b * DIM + g * GC + ccp) * Hs + hh) * Ws + wc;
                v0 = x[base];
                v1 = x[base + 8 * (size_t)(Hs * Ws)];
            }
            xp2[buf][ccp][r][col] = (h2v){(_Float16)v0, (_Float16)v1};
        }
    };

    stage(0, 0);

    for (int g = 0; g < Gn; ++g) {
        int buf = g & 1;
        // ---- P1: conv2 via MFMA -> wgt2 (dup f16 pairs) ----
        f32x4 acc[4];
#pragma unroll
        for (int nt = 0; nt < 4; ++nt) acc[nt] = (f32x4){0.f, 0.f, 0.f, 0.f};
#pragma unroll
        for (int nt = 0; nt < 4; ++nt) {
            bf16x8 bf = *(const bf16x8*)&w2b[(size_t)(g * 49 + nt * 16 + l15) * CMID + l4 * 8];
            acc[nt] = mfma16(a_t, bf, acc[nt]);
        }
#pragma unroll
        for (int nt = 0; nt < 4; ++nt) {
            int p = nt * 16 + l15;
            if (p < 49) {
                float bias = b2v[g * 49 + p];
#pragma unroll
                for (int r = 0; r < 4; ++r) {
                    _Float16 hf = (_Float16)(acc[nt][r] + bias);
                    wgt2[p][m0 + l4 * 4 + r] = (h2v){hf, hf};
                }
            }
        }
        __syncthreads();   // wgt2 ready; xp2[buf] staging (prev iter) complete

        // ---- P2: prefetch next stage + involution ----
        if (g < Gn - 1) stage(g + 1, buf ^ 1);

        h2v wv[49];
#pragma unroll
        for (int p = 0; p < 49; ++p) wv[p] = wgt2[p][w];

#pragma unroll
        for (int pi = 0; pi < 2; ++pi) {
            int ccp = q + pi * 4;
            float acc0 = 0.f, acc1 = 0.f;
#pragma unroll
            for (int r = 0; r < 7; ++r) {
                h2v hacc = (h2v){(_Float16)0.f, (_Float16)0.f};
#pragma unroll
                for (int j = 0; j < 7; ++j)
                    hacc = wv[r * 7 + j] * xp2[buf][ccp][r][w + j] + hacc;
                acc0 += (float)hacc.x;
                acc1 += (float)hacc.y;
            }
            ysb[g * GC + ccp][w]     = __float2bfloat16(acc0);
            ysb[g * GC + ccp + 8][w] = __float2bfloat16(acc1);
        }
        __syncthreads();   // xp2[buf^1] writes done block-wide; wgt2 free
    }

    // ---- LayerNorm ----
    {
        int part = tid >> 6;
        float s = 0.f, ss = 0.f;
#pragma unroll
        for (int c = 0; c < 32; ++c) {
            float v = __bfloat162float(ysb[part * 32 + c][w]);
            s += v; ss = fmaf(v, v, ss);
        }
        ps[part][w] = s; pss[part][w] = ss;
    }
    __syncthreads();
    if (tid < 64) {
        float s = ps[0][tid] + ps[1][tid] + ps[2][tid] + ps[3][tid];
        float ss = pss[0][tid] + pss[1][tid] + pss[2][tid] + pss[3][tid];
        float mu = s * (1.f / DIM);
        float var = ss * (1.f / DIM) - mu * mu;
        mu_s[tid] = mu;
        rs_s[tid] = rsqrtf(var + 1e-6f);
    }
    __syncthreads();
    for (int i = tid; i < Ws * DIM; i += 256) {
        int ww = i >> 7, c = i & 127;
        float v = (__bfloat162float(ysb[c][ww]) - mu_s[ww]) * rs_s[ww] * lng[c] + lnb[c];
        yln[(pbase + ww) * DIM + c] = __float2bfloat16(v);
    }
}

// ---------------- K3: MLP via bf16 MFMA + residual ----------------
__global__ __launch_bounds__(256) void k3_mlp_mfma(
        const __hip_bfloat16* __restrict__ yln,   // [P][128] bf16
        const float* __restrict__ x,
        const __hip_bfloat16* __restrict__ w1b,   // [256][128] bf16
        const float* __restrict__ b1v,
        const __hip_bfloat16* __restrict__ w2b,   // [128][256] bf16
        const float* __restrict__ b2v,
        float* __restrict__ out) {
    __shared__ __align__(16) union {
        __hip_bfloat16 y[64][136];
        float          o[64][133];
    } u;
    __shared__ __align__(16) __hip_bfloat16 zsh[4][16][264];

    int b = blockIdx.x & 7, h = blockIdx.x >> 3;   // XCD-aware
    int tid = threadIdx.x;
    int lane = tid & 63, wid = tid >> 6;
    int l15 = lane & 15, l4 = lane >> 4;
    size_t pbase = ((size_t)b * Hs + h) * Ws;

    for (int i = tid; i < 64 * 16; i += 256) {
        int row = i >> 4, ch = i & 15;
        *(ulonglong2*)&u.y[row][ch * 8] =
            *(const ulonglong2*)&yln[(pbase + row) * DIM + ch * 8];
    }
    __syncthreads();

    int m0 = wid * 16;

    f32x4 acc[16];
#pragma unroll
    for (int n = 0; n < 16; ++n) acc[n] = (f32x4){0.f, 0.f, 0.f, 0.f};
#pragma unroll
    for (int ks = 0; ks < 4; ++ks) {
        bf16x8 a = *(const bf16x8*)&u.y[m0 + l15][ks * 32 + l4 * 8];
#pragma unroll
        for (int n = 0; n < 16; ++n) {
            bf16x8 bf = *(const bf16x8*)&w1b[(n * 16 + l15) * DIM + ks * 32 + l4 * 8];
            acc[n] = mfma16(a, bf, acc[n]);
        }
    }
    __syncthreads();

#pragma unroll
    for (int n = 0; n < 16; ++n) {
        float bv = b1v[n * 16 + l15];
#pragma unroll
        for (int r = 0; r < 4; ++r) {
            float v = acc[n][r] + bv;
            v = v * 0.5f * (1.f + erff(v * 0.70710678118f));
            zsh[wid][l4 * 4 + r][n * 16 + l15] = __float2bfloat16(v);
        }
    }

    f32x4 acc2[8];
#pragma unroll
    for (int n = 0; n < 8; ++n) acc2[n] = (f32x4){0.f, 0.f, 0.f, 0.f};
#pragma unroll
    for (int ks = 0; ks < 8; ++ks) {
        bf16x8 a = *(const bf16x8*)&zsh[wid][l15][ks * 32 + l4 * 8];
#pragma unroll
        for (int n = 0; n < 8; ++n) {
            bf16x8 bf = *(const bf16x8*)&w2b[(n * 16 + l15) * 256 + ks * 32 + l4 * 8];
            acc2[n] = mfma16(a, bf, acc2[n]);
        }
    }

#pragma unroll
    for (int n = 0; n < 8; ++n) {
        float bv = b2v[n * 16 + l15];
#pragma unroll
        for (int r = 0; r < 4; ++r)
            u.o[m0 + l4 * 4 + r][n * 16 + l15] = acc2[n][r] + bv;
    }
    __syncthreads();

    for (int i = tid; i < Ws * DIM; i += 256) {
        int c = i >> 6, w = i & 63;
        size_t gi = (((size_t)b * DIM + c) * Hs + h) * Ws + w;
        out[gi] = u.o[w][c] + x[gi];
    }
}

extern "C" void kernel_launch(void* const* d_in, const int* in_sizes, int n_in,
                              void* d_out, int out_size, void* d_ws, size_t ws_size,
                              hipStream_t stream) {
    const float* x       = (const float*)d_in[0];
    const float* conv1_w = (const float*)d_in[1];
    const float* conv1_b = (const float*)d_in[2];
    const float* bn_g    = (const float*)d_in[3];
    const float* bn_b    = (const float*)d_in[4];
    const float* bn_mean = (const float*)d_in[5];
    const float* bn_var  = (const float*)d_in[6];
    const float* conv2_w = (const float*)d_in[7];
    const float* conv2_b = (const float*)d_in[8];
    const float* ln_g    = (const float*)d_in[9];
    const float* ln_b    = (const float*)d_in[10];
    const float* pw1_w   = (const float*)d_in[11];
    const float* pw1_b   = (const float*)d_in[12];
    const float* pw2_w   = (const float*)d_in[13];
    const float* pw2_b   = (const float*)d_in[14];
    float* out = (float*)d_out;

    char* ws = (char*)d_ws;
    __hip_bfloat16* t_bf = (__hip_bfloat16*)ws;                      // 2 MB
    __hip_bfloat16* y_ln = (__hip_bfloat16*)(ws + 2097152);          // 8 MB
    __hip_bfloat16* w1b  = (__hip_bfloat16*)(ws + 10485760);         // 8 KB
    __hip_bfloat16* w2b  = (__hip_bfloat16*)(ws + 10493952);         // 26 KB
    __hip_bfloat16* mw1b = (__hip_bfloat16*)(ws + 10520576);         // 64 KB
    __hip_bfloat16* mw2b = (__hip_bfloat16*)(ws + 10586112);         // 64 KB

    dim3 block(256);
    hipLaunchKernelGGL(k0_cvt, dim3(128), block, 0, stream,
                       conv1_w, conv2_w, pw1_w, pw2_w, w1b, w2b, mw1b, mw2b);
    hipLaunchKernelGGL(k1_conv1, dim3(Bn * Hs), block, 0, stream,
                       x, w1b, conv1_b, bn_g, bn_b, bn_mean, bn_var, t_bf);
    hipLaunchKernelGGL(k2_inv_ln, dim3(Bn * Hs), block, 0, stream,
                       x, t_bf, w2b, conv2_b, ln_g, ln_b, y_ln);
    hipLaunchKernelGGL(k3_mlp_mfma, dim3(Bn * Hs), block, 0, stream,
                       y_ln, x, mw1b, pw1_b, mw2b, pw2_b, out);
}